// Round 4
// baseline (547.334 us; speedup 1.0000x reference)
//
#include <hip/hip_runtime.h>

typedef unsigned int u32;
typedef unsigned short u16;
typedef __attribute__((ext_vector_type(8))) short short8;
typedef __attribute__((ext_vector_type(4))) float f32x4;

#define DD 128
#define RREL 8
#define NKT 9      // k-tiles: [root | W0..W7], 128 k each
#define SCAN_CHUNK 4096

static __device__ __forceinline__ u16 f2bf(float f) {
  u32 u = __builtin_bit_cast(u32, f);
  u32 r = (u + 0x7fffu + ((u >> 16) & 1u)) >> 16;
  return (u16)r;
}
static __device__ __forceinline__ float bflo(u32 v) { return __builtin_bit_cast(float, v << 16); }
static __device__ __forceinline__ float bfhi(u32 v) { return __builtin_bit_cast(float, v & 0xffff0000u); }

// ---- build pre-swizzled transposed weights for linear global_load_lds staging.
// wt[l][kt][pos] (16B chunks): pos = col*16 + cbx holds chunk (col, cb=cbx^(col&7)),
// chunk (col,cb) = 8 bf16 of column `col` at k = kt*128 + cb*8 .. +8, k-space = [root | W0..W7].
__global__ __launch_bounds__(256) void k_convw(const float* __restrict__ W,
                                               const float* __restrict__ root,
                                               uint4* __restrict__ wt) {
  int t = blockIdx.x * 256 + threadIdx.x;
  if (t >= 2 * NKT * 2048) return;
  int l = t / (NKT * 2048);
  int rem = t - l * (NKT * 2048);
  int kt = rem >> 11;
  int pos = rem & 2047;
  int col = pos >> 4;
  int cbx = pos & 15;
  int cb = cbx ^ (col & 7);
  int k0 = kt * DD + cb * 8;
  u16 vals[8];
#pragma unroll
  for (int i = 0; i < 8; ++i) {
    int k = k0 + i;
    float v;
    if (k < DD) {
      v = root[(size_t)l * DD * DD + k * DD + col];
    } else {
      int km = k - DD;
      v = W[((size_t)l * RREL + (km >> 7)) * DD * DD + (size_t)(km & 127) * DD + col];
    }
    vals[i] = f2bf(v);
  }
  wt[t] = *(uint4*)vals;
}

// ---- h0 = bf16(emb[x]) dense [N][128]
__global__ __launch_bounds__(256) void k_gather(const int* __restrict__ x,
                                                const float* __restrict__ emb,
                                                u16* __restrict__ h0, int N) {
  int t = blockIdx.x * 256 + threadIdx.x;
  if (t >= N * 16) return;
  int node = t >> 4, part = t & 15;
  const float4* e4 = (const float4*)(emb + (size_t)x[node] * DD + part * 8);
  float4 f0 = e4[0], f1 = e4[1];
  uint4 u;
  u.x = (u32)f2bf(f0.x) | ((u32)f2bf(f0.y) << 16);
  u.y = (u32)f2bf(f0.z) | ((u32)f2bf(f0.w) << 16);
  u.z = (u32)f2bf(f1.x) | ((u32)f2bf(f1.y) << 16);
  u.w = (u32)f2bf(f1.z) | ((u32)f2bf(f1.w) << 16);
  *(uint4*)(h0 + (size_t)node * DD + part * 8) = u;
}

// ---- histogram over segments seg = dst*8 + etype, 4 edges/thread for ILP
__global__ __launch_bounds__(256) void k_hist(const int* __restrict__ ei,
                                              const int* __restrict__ et,
                                              int* __restrict__ cnt, int E) {
  int base = (blockIdx.x * 256 + threadIdx.x) * 4;
  if (base + 3 < E) {
    int4 d4 = *(const int4*)(ei + E + base);
    int4 t4 = *(const int4*)(et + base);
    atomicAdd(&cnt[d4.x * 8 + t4.x], 1);
    atomicAdd(&cnt[d4.y * 8 + t4.y], 1);
    atomicAdd(&cnt[d4.z * 8 + t4.z], 1);
    atomicAdd(&cnt[d4.w * 8 + t4.w], 1);
  } else {
    for (int e = base; e < E; ++e) atomicAdd(&cnt[ei[E + e] * 8 + et[e]], 1);
  }
}

__global__ __launch_bounds__(256) void k_scan_reduce(const int* __restrict__ cnt,
                                                     int* __restrict__ blksum, int nseg) {
  __shared__ int s[256];
  int b = blockIdx.x, t = threadIdx.x;
  int base = b * SCAN_CHUNK;
  int sum = 0;
  for (int i = 0; i < 16; ++i) {
    int idx = base + i * 256 + t;
    if (idx < nseg) sum += cnt[idx];
  }
  s[t] = sum;
  __syncthreads();
  for (int st = 128; st > 0; st >>= 1) {
    if (t < st) s[t] += s[t + st];
    __syncthreads();
  }
  if (t == 0) blksum[b] = s[0];
}

__global__ void k_scan_top(int* __restrict__ blksum, int nblk, int* __restrict__ off,
                           int nseg, int E) {
  if (threadIdx.x == 0 && blockIdx.x == 0) {
    int run = 0;
    for (int b = 0; b < nblk; ++b) { int v = blksum[b]; blksum[b] = run; run += v; }
    off[nseg] = E;
  }
}

__global__ __launch_bounds__(256) void k_scan_write(const int* __restrict__ cnt,
                                                    const int* __restrict__ blksum,
                                                    int* __restrict__ off, int nseg) {
  __shared__ int s[256];
  int b = blockIdx.x, t = threadIdx.x;
  int base = b * SCAN_CHUNK + t * 16;
  int v[16];
  int sum = 0;
#pragma unroll
  for (int i = 0; i < 16; ++i) {
    int idx = base + i;
    v[i] = (idx < nseg) ? cnt[idx] : 0;
    sum += v[i];
  }
  s[t] = sum;
  __syncthreads();
  for (int st = 1; st < 256; st <<= 1) {
    int add = (t >= st) ? s[t - st] : 0;
    __syncthreads();
    s[t] += add;
    __syncthreads();
  }
  int run = blksum[b] + s[t] - sum;
#pragma unroll
  for (int i = 0; i < 16; ++i) {
    int idx = base + i;
    if (idx < nseg) off[idx] = run;
    run += v[i];
  }
}

// ---- scatter: fill starts as a copy of off; pos = atomicAdd(&fill[seg],1). 4 edges/thread.
__global__ __launch_bounds__(256) void k_scatter(const int* __restrict__ ei,
                                                 const int* __restrict__ et,
                                                 int* __restrict__ fill,
                                                 int* __restrict__ sorted, int E) {
  int base = (blockIdx.x * 256 + threadIdx.x) * 4;
  if (base + 3 < E) {
    int4 s4 = *(const int4*)(ei + base);
    int4 d4 = *(const int4*)(ei + E + base);
    int4 t4 = *(const int4*)(et + base);
    int p0 = atomicAdd(&fill[d4.x * 8 + t4.x], 1);
    int p1 = atomicAdd(&fill[d4.y * 8 + t4.y], 1);
    int p2 = atomicAdd(&fill[d4.z * 8 + t4.z], 1);
    int p3 = atomicAdd(&fill[d4.w * 8 + t4.w], 1);
    sorted[p0] = s4.x;
    sorted[p1] = s4.y;
    sorted[p2] = s4.z;
    sorted[p3] = s4.w;
  } else {
    for (int e = base; e < E; ++e) {
      int pos = atomicAdd(&fill[ei[E + e] * 8 + et[e]], 1);
      sorted[pos] = ei[e];
    }
  }
}

static __device__ __forceinline__ void add8(float* a, uint4 v) {
  a[0] += bflo(v.x); a[1] += bfhi(v.x);
  a[2] += bflo(v.y); a[3] += bfhi(v.y);
  a[4] += bflo(v.z); a[5] += bfhi(v.z);
  a[6] += bflo(v.w); a[7] += bfhi(v.w);
}

// ---- fused layer: out[row] = relu( [h | mean_r(h[src])] @ Wcat + bias )
// 128 rows/block, 8 waves of 64. Per wave: 16 rows; lane = p + 16q owns row p,
// feature chunk q*8 within each 32-feat kc block -> aggregation accumulates DIRECTLY
// in MFMA A-fragment layout (no LDS transpose, no Am materialization).
// B k-tiles (32KB, pre-swizzled) double-buffered in LDS via global_load_lds.
template <bool LAST>
__global__ __launch_bounds__(512, 4) void k_fused(const u16* __restrict__ hin,
                                                  const int* __restrict__ off,
                                                  const int* __restrict__ sorted,
                                                  const uint4* __restrict__ wt,
                                                  const float* __restrict__ bias,
                                                  u16* __restrict__ hout,
                                                  float* __restrict__ dout, int M) {
  __shared__ uint4 ldsB[2][2048];  // 2 x 32KB
  int tid = threadIdx.x, wave = tid >> 6, lane = tid & 63;
  int p = lane & 15, q = lane >> 4;
  int row = blockIdx.x * 128 + wave * 16 + p;
  int arc = row < M ? row : M - 1;
  f32x4 acc[8];
#pragma unroll
  for (int c = 0; c < 8; ++c) acc[c] = (f32x4)0.f;

#define STAGE(KT, BUF)                                                                   \
  do {                                                                                   \
    const uint4* gsrc = wt + (size_t)(KT) * 2048;                                        \
    _Pragma("unroll") for (int i_ = 0; i_ < 4; ++i_) {                                   \
      int cid_ = i_ * 512 + tid;                                                         \
      __builtin_amdgcn_global_load_lds(                                                  \
          (const __attribute__((address_space(1))) uint4*)(gsrc + cid_),                 \
          (__attribute__((address_space(3))) uint4*)&ldsB[BUF][cid_], 16, 0, 0);         \
    }                                                                                    \
  } while (0)

  STAGE(0, 0);
  for (int kt = 0; kt < NKT; ++kt) {
    short8 afrag[4];
    if (kt == 0) {
      // root path: A = h[row] directly
      const short8* ap = (const short8*)(hin + (size_t)arc * DD) + q;
#pragma unroll
      for (int kc = 0; kc < 4; ++kc) afrag[kc] = ap[kc * 4];
    } else {
      int r = kt - 1;
      int s = 0, e = 0;
      if (row < M) {
        int sb = row * 8 + r;
        s = off[sb];
        e = off[sb + 1];
      }
      float a[32];
#pragma unroll
      for (int i = 0; i < 32; ++i) a[i] = 0.f;
      for (int j = s; j < e; ++j) {
        int src = sorted[j];
        const uint4* hp = (const uint4*)(hin + (size_t)src * DD) + q;
        uint4 v0 = hp[0], v1 = hp[4], v2 = hp[8], v3 = hp[12];
        add8(a + 0, v0);
        add8(a + 8, v1);
        add8(a + 16, v2);
        add8(a + 24, v3);
      }
      float norm = (e > s) ? 1.0f / (float)(e - s) : 0.f;
      u16 fr[32];
#pragma unroll
      for (int i = 0; i < 32; ++i) fr[i] = f2bf(a[i] * norm);
#pragma unroll
      for (int kc = 0; kc < 4; ++kc) afrag[kc] = *(const short8*)(fr + kc * 8);
    }
    int cur = kt & 1;
    __syncthreads();  // drains vmcnt -> buf[cur] staged; syncs reuse of buf[cur^1]
    if (kt + 1 < NKT) STAGE(kt + 1, cur ^ 1);
#pragma unroll
    for (int kc = 0; kc < 4; ++kc) {
      int chunk = kc * 4 + q;
#pragma unroll
      for (int c = 0; c < 8; ++c) {
        int col = c * 16 + p;
        const short8* bp = (const short8*)&ldsB[cur][col * 16 + (chunk ^ (col & 7))];
        acc[c] = __builtin_amdgcn_mfma_f32_16x16x32_bf16(afrag[kc], *bp, acc[c], 0, 0, 0);
      }
    }
  }
#undef STAGE

  int crow0 = blockIdx.x * 128 + wave * 16 + (q << 2);
#pragma unroll
  for (int c = 0; c < 8; ++c) {
    int col = c * 16 + p;
    float bv = bias[col];
#pragma unroll
    for (int i = 0; i < 4; ++i) {
      int rw = crow0 + i;
      if (rw < M) {
        float v = fmaxf(acc[c][i] + bv, 0.f);
        if (LAST) dout[(size_t)rw * DD + col] = v;
        else hout[(size_t)rw * DD + col] = f2bf(v);
      }
    }
  }
}

extern "C" void kernel_launch(void* const* d_in, const int* in_sizes, int n_in,
                              void* d_out, int out_size, void* d_ws, size_t ws_size,
                              hipStream_t stream) {
  const int* x = (const int*)d_in[0];
  const int* ei = (const int*)d_in[1];
  const int* et = (const int*)d_in[2];
  const float* emb = (const float*)d_in[3];
  const float* W = (const float*)d_in[4];
  const float* root = (const float*)d_in[5];
  const float* bias = (const float*)d_in[6];

  const int N = in_sizes[0];
  const int E = in_sizes[2];
  const int NSEG = N * RREL;

  size_t o = 0;
  auto al = [&](size_t b) { size_t r = o; o = (o + b + 255) & ~(size_t)255; return r; };
  size_t off_o = al(((size_t)NSEG + 1) * 4);
  size_t cnt_o = al((size_t)NSEG * 4);
  size_t fill_o = al((size_t)NSEG * 4);
  size_t sorted_o = al((size_t)E * 4);
  size_t blk_o = al(4096);
  size_t wt_o = al((size_t)2 * NKT * 2048 * 16);
  size_t h0_o = al((size_t)N * DD * 2);
  size_t h1_o = al((size_t)N * DD * 2);
  (void)h1_o;

  char* ws = (char*)d_ws;
  int* off = (int*)(ws + off_o);
  int* cnt = (int*)(ws + cnt_o);
  int* fill = (int*)(ws + fill_o);
  int* sorted = (int*)(ws + sorted_o);
  int* blks = (int*)(ws + blk_o);
  uint4* wt = (uint4*)(ws + wt_o);
  u16* h0 = (u16*)(ws + h0_o);
  u16* h1 = (u16*)(ws + h1_o);
  float* outf = (float*)d_out;

  // ---- prep
  k_convw<<<(2 * NKT * 2048 + 255) / 256, 256, 0, stream>>>(W, root, wt);
  k_gather<<<(N * 16 + 255) / 256, 256, 0, stream>>>(x, emb, h0, N);
  hipMemsetAsync(cnt, 0, (size_t)NSEG * 4, stream);
  int egrid = ((E + 3) / 4 + 255) / 256;
  k_hist<<<egrid, 256, 0, stream>>>(ei, et, cnt, E);
  int nblk = (NSEG + SCAN_CHUNK - 1) / SCAN_CHUNK;
  k_scan_reduce<<<nblk, 256, 0, stream>>>(cnt, blks, NSEG);
  k_scan_top<<<1, 64, 0, stream>>>(blks, nblk, off, NSEG, E);
  k_scan_write<<<nblk, 256, 0, stream>>>(cnt, blks, off, NSEG);
  hipMemcpyAsync(fill, off, (size_t)NSEG * 4, hipMemcpyDeviceToDevice, stream);
  k_scatter<<<egrid, 256, 0, stream>>>(ei, et, fill, sorted, E);

  // ---- fused layers
  int gx = (N + 127) / 128;
  k_fused<false><<<gx, 512, 0, stream>>>(h0, off, sorted, wt, bias, h1, nullptr, N);
  k_fused<true><<<gx, 512, 0, stream>>>(h1, off, sorted, wt + (size_t)NKT * 2048,
                                        bias + DD, nullptr, outf, N);
}